// Round 5
// baseline (254.772 us; speedup 1.0000x reference)
//
#include <hip/hip_runtime.h>
#include <math.h>

// Problem constants
#define NTHREADS 256
#define TROWS 16            // rows (tokens) per block = one 16-row MFMA tile
#define TOKN 13824          // 24*24*24
#define MASKN 10368         // 0.75 * TOKN
#define UNMASKN 3456        // TOKN - MASKN
#define EMB 768
#define NPOS 24
#define NBATCH 4
#define ABLOCKS (TOKN / TROWS)            // 864 (4 batches * 3456 unmask rows)
#define BBLOCKS (MASKN / TROWS)           // 648 mask row-groups
#define TOTBLOCKS (ABLOCKS + NBATCH * BBLOCKS)   // 864 + 2592 = 3456, uniform work
#define TABN (NPOS * 256)         // 6144 floats = 24 KB sincos table in d_ws
#define WN (64 * EMB)             // 49152 W elements
#define LROW 388                  // LDS out-stage row stride (384 + 4 pad floats)

typedef __attribute__((ext_vector_type(8))) short short8;   // 8 bf16 = 4 VGPRs
typedef __attribute__((ext_vector_type(4))) float f32x4;

__device__ __forceinline__ short f2bf(float f) {
  union { float f; unsigned u; } c; c.f = f;
  unsigned u = c.u + 0x7FFFu + ((c.u >> 16) & 1u);   // RNE
  return (short)(u >> 16);
}

// Setup: sincos table + bf16-transposed W (wsW[col][k]) in d_ws + mask_idx out.
__global__ __launch_bounds__(NTHREADS) void setup_kernel(
    const float* __restrict__ W, const int* __restrict__ perm,
    float* __restrict__ tabg, short* __restrict__ wsW,
    float* __restrict__ out_idx)
{
  int i = blockIdx.x * NTHREADS + threadIdx.x;
  if (i < MASKN) out_idx[i] = (float)perm[i];
  if (i < TABN) {
    // inv_freq[j] = 10000^(-j/128) = 2^(-j * log2(10000)/128)
    const float c0 = 13.287712379549449f / 128.0f;
    int pos = i >> 8, e = i & 255, j = e >> 1;
    float s = (float)pos * exp2f(-(float)j * c0);
    tabg[i] = (e & 1) ? cosf(s) : sinf(s);
  }
  if (i < WN) {
    int col = i >> 6, k = i & 63;
    wsW[i] = f2bf(W[k * EMB + col]);   // wsW[col*64 + k]
  }
}

// Round-3: SWAPPED MFMA operands — C/D holds token = lane&15, 4 consecutive
// cols in the reg index.
// Round-5: plain f32x4 stores (nt defeated L2 write-combining, +10us).
// Round-6: lb(256,4), 2 barriers — neutral. Epilogue variants all ~neutral:
// the kernel is pinned ~100us regardless -> write PATH, not instructions.
// Round-7 THEORY: all prior versions stored 16 scattered 64B half-line
// segments per instruction (row stride 3072B) -> partial-line L2/HBM writes
// throttle to ~1.7 TB/s (fill does 6.7 TB/s with full lines).
// FIX: (a) stage normalized output in LDS (2 chunks of 16x384), stream out as
// perfectly sequential 4KB passes = all full 128B lines; (b) split mask
// blocks per batch-copy (grid 3456, every block stores exactly 48KB once).
__global__ __launch_bounds__(NTHREADS, 4) void fused_embed_ln_mfma(
    const float* __restrict__ x, const float* __restrict__ pb,
    const float* __restrict__ mt, const float* __restrict__ gmm,
    const float* __restrict__ bta, const int* __restrict__ perm,
    const float* __restrict__ tabg, const short* __restrict__ wsW,
    float* __restrict__ out)
{
  __shared__ __align__(16) float ldsOut[TROWS * LROW];  // 24.8 KB out-stage
  __shared__ __align__(16) short aLds[TROWS][72];       // bf16 A, +8 pad
  __shared__ int segbase[3][TROWS];                     // h/w/d << 8 per row
  __shared__ float wred[TROWS][4][2];

  const int tid = threadIdx.x;
  const int blk = blockIdx.x;
  const bool isA = blk < ABLOCKS;
  const int blkb = blk - ABLOCKS;                  // B-blocks: [0, 2592)
  const int copy = isA ? 0 : (blkb / BBLOCKS);     // which batch copy
  const int bidx = isA ? 0 : (blkb % BBLOCKS);     // mask row-group

  // --- stage 16 patch rows into LDS as bf16; every lane redundantly computes
  // its row's token index + (h,w,d) so only ONE barrier is needed ---
  {
    int t = tid >> 4, seg = tid & 15;
    int r;
    if (isA) {
      r = perm[MASKN + (blk * TROWS) % UNMASKN + t];  // 3456%16==0: 1 batch/blk
    } else {
      r = perm[bidx * TROWS + t];
    }
    int h = r / 576; int rem = r - h * 576;
    int w = rem / 24; int d = rem - w * 24;
    if (seg < 3) segbase[seg][t] = (seg == 0 ? h : (seg == 1 ? w : d)) << 8;

    float4 v;
    if (isA) {
      int b = (blk * TROWS) / UNMASKN;
      int ph = seg >> 2, pw = seg & 3;
      v = *(const float4*)(x +
          ((((long)b * 96 + h * 4 + ph) * 96 + (w * 4 + pw)) * 96 + d * 4));
    } else {
      v = *(const float4*)(mt + (long)(bidx * TROWS + t) * 64 + seg * 4);
    }
    short4 s4; s4.x = f2bf(v.x); s4.y = f2bf(v.y); s4.z = f2bf(v.z); s4.w = f2bf(v.w);
    *(short4*)&aLds[t][seg * 4] = s4;
  }
  __syncthreads();                                   // barrier #1

  // --- MFMA GEMM: wave wv covers cols [wv*192, wv*192+192) = 12 tiles ---
  const int wv = tid >> 6, lane = tid & 63;
  const int n16 = lane & 15, q = lane >> 4;
  const int q4 = q * 4;
  const int colbase = wv * 192;

  // Patch frag (operand B after swap): B[k=q*8+j][col=n16]
  short8 af0 = *(const short8*)&aLds[n16][q * 8];
  short8 af1 = *(const short8*)&aLds[n16][32 + q * 8];

  f32x4 acc[12];
  const short* wp = wsW + (colbase + n16) * 64 + q * 8;
  #pragma unroll
  for (int jt = 0; jt < 12; ++jt) {
    // W frag (operand A after swap): A[row -> col colbase+jt*16+n16][k=q*8+j]
    short8 bf0 = *(const short8*)(wp + jt * 16 * 64);
    short8 bf1 = *(const short8*)(wp + jt * 16 * 64 + 32);
    f32x4 c = {0.f, 0.f, 0.f, 0.f};
    c = __builtin_amdgcn_mfma_f32_16x16x32_bf16(bf0, af0, c, 0, 0, 0);
    c = __builtin_amdgcn_mfma_f32_16x16x32_bf16(bf1, af1, c, 0, 0, 0);
    acc[jt] = c;   // acc[jt][r] = out[token=n16][col = colbase + jt*16 + q4 + r]
  }

  // --- add bias + pos-enc (float4), per-token LN partials ---
  // 16-aligned tiles / 4-aligned reg groups never cross a 256-col segment.
  const float* t0 = tabg + segbase[0][n16];
  const float* t1 = tabg + segbase[1][n16];
  const float* t2 = tabg + segbase[2][n16];

  float s = 0.f, qq = 0.f;
  #pragma unroll
  for (int jt = 0; jt < 12; ++jt) {
    int colb = colbase + jt * 16 + q4;
    int seg = colb >> 8;
    int cb = colb & 255;
    const float* tp = (seg == 0) ? t0 : ((seg == 1) ? t1 : t2);
    f32x4 pbv = *(const f32x4*)(pb + colb);
    f32x4 tv  = *(const f32x4*)(tp + cb);
    float v0 = acc[jt][0] + pbv[0] + tv[0];
    float v1 = acc[jt][1] + pbv[1] + tv[1];
    float v2 = acc[jt][2] + pbv[2] + tv[2];
    float v3 = acc[jt][3] + pbv[3] + tv[3];
    acc[jt][0] = v0; acc[jt][1] = v1; acc[jt][2] = v2; acc[jt][3] = v3;
    s  += (v0 + v1) + (v2 + v3);
    qq += (v0 * v0 + v1 * v1) + (v2 * v2 + v3 * v3);
  }
  // token row lives in n16; reduce across q (lane bits 4,5) only
  s  += __shfl_xor(s,  16, 64);
  s  += __shfl_xor(s,  32, 64);
  qq += __shfl_xor(qq, 16, 64);
  qq += __shfl_xor(qq, 32, 64);
  if (lane < 16) { wred[lane][wv][0] = s; wred[lane][wv][1] = qq; }
  __syncthreads();                                   // barrier #2

  // every lane computes its row's stats from the 4 wave partials
  float ss = wred[n16][0][0] + wred[n16][1][0] + wred[n16][2][0] + wred[n16][3][0];
  float qs = wred[n16][0][1] + wred[n16][1][1] + wred[n16][2][1] + wred[n16][3][1];
  float mean = ss * (1.0f / 768.0f);
  float var = qs * (1.0f / 768.0f) - mean * mean;    // biased, matches jnp.var
  float rstd = 1.0f / sqrtf(var + 0.001f);           // LN_EPS

  // --- normalize into LDS chunks, then fully-coalesced full-line stores ---
  long rowbase;
  if (isA) {
    int row0 = blk * TROWS;
    rowbase = (long)(row0 / UNMASKN) * TOKN + (row0 % UNMASKN);
  } else {
    rowbase = (long)copy * TOKN + UNMASKN + bidx * TROWS;
  }
  float* gbase = out + rowbase * EMB;
  const int mychunk = wv >> 1;   // waves 0,1 -> cols [0,384); waves 2,3 -> [384,768)

  #pragma unroll
  for (int c = 0; c < 2; ++c) {
    if (mychunk == c) {
      #pragma unroll
      for (int jt = 0; jt < 12; ++jt) {
        int colb = colbase + jt * 16 + q4;
        f32x4 g  = *(const f32x4*)(gmm + colb);
        f32x4 bb = *(const f32x4*)(bta + colb);
        f32x4 o;
        #pragma unroll
        for (int r = 0; r < 4; ++r) {
          float sc = rstd * g[r];
          o[r] = acc[jt][r] * sc + (bb[r] - mean * sc);
        }
        *(f32x4*)&ldsOut[n16 * LROW + (colb - c * 384)] = o;
      }
    }
    __syncthreads();   // chunk data visible
    // 6 passes x 256 threads x 16B = 24 KB; each pass = sequential 4 KB,
    // every segment a full aligned 128B line (row = 1536B = 12 lines).
    #pragma unroll
    for (int p = 0; p < 6; ++p) {
      int idx = p * 256 + tid;          // 0..1535 (16B units)
      int row = idx / 96;
      int off = idx - row * 96;         // 0..95
      f32x4 v = *(const f32x4*)&ldsOut[row * LROW + off * 4];
      *(f32x4*)(gbase + (long)row * EMB + c * 384 + off * 4) = v;
    }
    if (c == 0) __syncthreads();        // before chunk-1 reuses the buffer
  }
}

extern "C" void kernel_launch(void* const* d_in, const int* in_sizes, int n_in,
                              void* d_out, int out_size, void* d_ws, size_t ws_size,
                              hipStream_t stream) {
  const float* x    = (const float*)d_in[0];
  const float* W    = (const float*)d_in[1];
  const float* pb   = (const float*)d_in[2];
  const float* mt   = (const float*)d_in[3];
  const float* gmm  = (const float*)d_in[4];
  const float* bta  = (const float*)d_in[5];
  const int*   perm = (const int*)d_in[6];
  float* out = (float*)d_out;
  float* out_idx = out + (long)NBATCH * TOKN * EMB;   // 42,467,328

  float* tabg = (float*)d_ws;                         // 24 KB sincos table
  short* wsW  = (short*)((char*)d_ws + TABN * 4);     // 96 KB bf16 W^T [col][k]

  setup_kernel<<<(WN + NTHREADS - 1) / NTHREADS, NTHREADS, 0, stream>>>(
      W, perm, tabg, wsW, out_idx);
  fused_embed_ln_mfma<<<TOTBLOCKS, NTHREADS, 0, stream>>>(
      x, pb, mt, gmm, bta, perm, tabg, wsW, out);
}

// Round 6
// 249.422 us; speedup vs baseline: 1.0215x; 1.0215x over previous
//
#include <hip/hip_runtime.h>
#include <math.h>

// Problem constants
#define NTHREADS 256
#define TROWS 16            // rows (tokens) per block = one 16-row MFMA tile
#define TOKN 13824          // 24*24*24
#define MASKN 10368         // 0.75 * TOKN
#define UNMASKN 3456        // TOKN - MASKN
#define EMB 768
#define NPOS 24
#define NBATCH 4
#define ABLOCKS (TOKN / TROWS)            // 864 (4 batches * 3456 unmask rows)
#define BBLOCKS (MASKN / TROWS)           // 648 mask row-groups
#define TOTBLOCKS (ABLOCKS + NBATCH * BBLOCKS)   // 864 + 2592 = 3456, uniform work
#define TABN (NPOS * 256)         // 6144 floats = 24 KB sincos table in d_ws
#define WN (64 * EMB)             // 49152 W elements
#define LROW 388                  // LDS out-stage row stride (384 + 4 pad floats)

typedef __attribute__((ext_vector_type(8))) short short8;   // 8 bf16 = 4 VGPRs
typedef __attribute__((ext_vector_type(4))) float f32x4;

__device__ __forceinline__ short f2bf(float f) {
  union { float f; unsigned u; } c; c.f = f;
  unsigned u = c.u + 0x7FFFu + ((c.u >> 16) & 1u);   // RNE
  return (short)(u >> 16);
}

// Setup: sincos table + bf16-transposed W (wsW[col][k]) in d_ws + mask_idx out.
__global__ __launch_bounds__(NTHREADS) void setup_kernel(
    const float* __restrict__ W, const int* __restrict__ perm,
    float* __restrict__ tabg, short* __restrict__ wsW,
    float* __restrict__ out_idx)
{
  int i = blockIdx.x * NTHREADS + threadIdx.x;
  if (i < MASKN) out_idx[i] = (float)perm[i];
  if (i < TABN) {
    // inv_freq[j] = 10000^(-j/128) = 2^(-j * log2(10000)/128)
    const float c0 = 13.287712379549449f / 128.0f;
    int pos = i >> 8, e = i & 255, j = e >> 1;
    float s = (float)pos * exp2f(-(float)j * c0);
    tabg[i] = (e & 1) ? cosf(s) : sinf(s);
  }
  if (i < WN) {
    int col = i >> 6, k = i & 63;
    wsW[i] = f2bf(W[k * EMB + col]);   // wsW[col*64 + k]
  }
}

// Round-3: SWAPPED MFMA operands — C/D holds token = lane&15, 4 consecutive
// cols in the reg index.
// Round-5: plain f32x4 stores (nt defeated L2 write-combining, +10us).
// Round-7: LDS-staged fully-coalesced stores + uniform 3456-block grid.
// Round-8 (R5 profile): VGPR_Count=64! The allocator chose the 8-waves/EU
// tier despite lb(256,4) allowing 128 regs, and spilled (FETCH +17MB,
// WRITE +27MB of scratch; MfmaUtil 1.9%, VALUBusy 12% -> spill-latency-bound).
// FIX: amdgpu_waves_per_eu(4,4) — min 4 keeps the 128-reg budget, MAX 4
// removes the incentive to squeeze to 64. acc[12]=48 regs + temps ~= 100
// fits in 128 with zero spill.
__global__ __launch_bounds__(NTHREADS)
__attribute__((amdgpu_waves_per_eu(4, 4)))
void fused_embed_ln_mfma(
    const float* __restrict__ x, const float* __restrict__ pb,
    const float* __restrict__ mt, const float* __restrict__ gmm,
    const float* __restrict__ bta, const int* __restrict__ perm,
    const float* __restrict__ tabg, const short* __restrict__ wsW,
    float* __restrict__ out)
{
  __shared__ __align__(16) float ldsOut[TROWS * LROW];  // 24.8 KB out-stage
  __shared__ __align__(16) short aLds[TROWS][72];       // bf16 A, +8 pad
  __shared__ int segbase[3][TROWS];                     // h/w/d << 8 per row
  __shared__ float wred[TROWS][4][2];

  const int tid = threadIdx.x;
  const int blk = blockIdx.x;
  const bool isA = blk < ABLOCKS;
  const int blkb = blk - ABLOCKS;                  // B-blocks: [0, 2592)
  const int copy = isA ? 0 : (blkb / BBLOCKS);     // which batch copy
  const int bidx = isA ? 0 : (blkb % BBLOCKS);     // mask row-group

  // --- stage 16 patch rows into LDS as bf16; every lane redundantly computes
  // its row's token index + (h,w,d) so only ONE barrier is needed ---
  {
    int t = tid >> 4, seg = tid & 15;
    int r;
    if (isA) {
      r = perm[MASKN + (blk * TROWS) % UNMASKN + t];  // 3456%16==0: 1 batch/blk
    } else {
      r = perm[bidx * TROWS + t];
    }
    int h = r / 576; int rem = r - h * 576;
    int w = rem / 24; int d = rem - w * 24;
    if (seg < 3) segbase[seg][t] = (seg == 0 ? h : (seg == 1 ? w : d)) << 8;

    float4 v;
    if (isA) {
      int b = (blk * TROWS) / UNMASKN;
      int ph = seg >> 2, pw = seg & 3;
      v = *(const float4*)(x +
          ((((long)b * 96 + h * 4 + ph) * 96 + (w * 4 + pw)) * 96 + d * 4));
    } else {
      v = *(const float4*)(mt + (long)(bidx * TROWS + t) * 64 + seg * 4);
    }
    short4 s4; s4.x = f2bf(v.x); s4.y = f2bf(v.y); s4.z = f2bf(v.z); s4.w = f2bf(v.w);
    *(short4*)&aLds[t][seg * 4] = s4;
  }
  __syncthreads();                                   // barrier #1

  // --- MFMA GEMM: wave wv covers cols [wv*192, wv*192+192) = 12 tiles ---
  const int wv = tid >> 6, lane = tid & 63;
  const int n16 = lane & 15, q = lane >> 4;
  const int q4 = q * 4;
  const int colbase = wv * 192;

  // Patch frag (operand B after swap): B[k=q*8+j][col=n16]
  short8 af0 = *(const short8*)&aLds[n16][q * 8];
  short8 af1 = *(const short8*)&aLds[n16][32 + q * 8];

  f32x4 acc[12];
  const short* wp = wsW + (colbase + n16) * 64 + q * 8;
  #pragma unroll
  for (int jt = 0; jt < 12; ++jt) {
    // W frag (operand A after swap): A[row -> col colbase+jt*16+n16][k=q*8+j]
    short8 bf0 = *(const short8*)(wp + jt * 16 * 64);
    short8 bf1 = *(const short8*)(wp + jt * 16 * 64 + 32);
    f32x4 c = {0.f, 0.f, 0.f, 0.f};
    c = __builtin_amdgcn_mfma_f32_16x16x32_bf16(bf0, af0, c, 0, 0, 0);
    c = __builtin_amdgcn_mfma_f32_16x16x32_bf16(bf1, af1, c, 0, 0, 0);
    acc[jt] = c;   // acc[jt][r] = out[token=n16][col = colbase + jt*16 + q4 + r]
  }

  // --- add bias + pos-enc (float4), per-token LN partials ---
  // 16-aligned tiles / 4-aligned reg groups never cross a 256-col segment.
  const float* t0 = tabg + segbase[0][n16];
  const float* t1 = tabg + segbase[1][n16];
  const float* t2 = tabg + segbase[2][n16];

  float s = 0.f, qq = 0.f;
  #pragma unroll
  for (int jt = 0; jt < 12; ++jt) {
    int colb = colbase + jt * 16 + q4;
    int seg = colb >> 8;
    int cb = colb & 255;
    const float* tp = (seg == 0) ? t0 : ((seg == 1) ? t1 : t2);
    f32x4 pbv = *(const f32x4*)(pb + colb);
    f32x4 tv  = *(const f32x4*)(tp + cb);
    float v0 = acc[jt][0] + pbv[0] + tv[0];
    float v1 = acc[jt][1] + pbv[1] + tv[1];
    float v2 = acc[jt][2] + pbv[2] + tv[2];
    float v3 = acc[jt][3] + pbv[3] + tv[3];
    acc[jt][0] = v0; acc[jt][1] = v1; acc[jt][2] = v2; acc[jt][3] = v3;
    s  += (v0 + v1) + (v2 + v3);
    qq += (v0 * v0 + v1 * v1) + (v2 * v2 + v3 * v3);
  }
  // token row lives in n16; reduce across q (lane bits 4,5) only
  s  += __shfl_xor(s,  16, 64);
  s  += __shfl_xor(s,  32, 64);
  qq += __shfl_xor(qq, 16, 64);
  qq += __shfl_xor(qq, 32, 64);
  if (lane < 16) { wred[lane][wv][0] = s; wred[lane][wv][1] = qq; }
  __syncthreads();                                   // barrier #2

  // every lane computes its row's stats from the 4 wave partials
  float ss = wred[n16][0][0] + wred[n16][1][0] + wred[n16][2][0] + wred[n16][3][0];
  float qs = wred[n16][0][1] + wred[n16][1][1] + wred[n16][2][1] + wred[n16][3][1];
  float mean = ss * (1.0f / 768.0f);
  float var = qs * (1.0f / 768.0f) - mean * mean;    // biased, matches jnp.var
  float rstd = 1.0f / sqrtf(var + 0.001f);           // LN_EPS

  // --- normalize into LDS chunks, then fully-coalesced full-line stores ---
  long rowbase;
  if (isA) {
    int row0 = blk * TROWS;
    rowbase = (long)(row0 / UNMASKN) * TOKN + (row0 % UNMASKN);
  } else {
    rowbase = (long)copy * TOKN + UNMASKN + bidx * TROWS;
  }
  float* gbase = out + rowbase * EMB;
  const int mychunk = wv >> 1;   // waves 0,1 -> cols [0,384); waves 2,3 -> [384,768)

  #pragma unroll
  for (int c = 0; c < 2; ++c) {
    if (mychunk == c) {
      #pragma unroll
      for (int jt = 0; jt < 12; ++jt) {
        int colb = colbase + jt * 16 + q4;
        f32x4 g  = *(const f32x4*)(gmm + colb);
        f32x4 bb = *(const f32x4*)(bta + colb);
        f32x4 o;
        #pragma unroll
        for (int r = 0; r < 4; ++r) {
          float sc = rstd * g[r];
          o[r] = acc[jt][r] * sc + (bb[r] - mean * sc);
        }
        *(f32x4*)&ldsOut[n16 * LROW + (colb - c * 384)] = o;
      }
    }
    __syncthreads();   // chunk data visible
    // 6 passes x 256 threads x 16B = 24 KB; each pass = sequential 4 KB,
    // every segment a full aligned 128B line (row = 1536B = 12 lines).
    #pragma unroll
    for (int p = 0; p < 6; ++p) {
      int idx = p * 256 + tid;          // 0..1535 (16B units)
      int row = idx / 96;
      int off = idx - row * 96;         // 0..95
      f32x4 v = *(const f32x4*)&ldsOut[row * LROW + off * 4];
      *(f32x4*)(gbase + (long)row * EMB + c * 384 + off * 4) = v;
    }
    if (c == 0) __syncthreads();        // before chunk-1 reuses the buffer
  }
}

extern "C" void kernel_launch(void* const* d_in, const int* in_sizes, int n_in,
                              void* d_out, int out_size, void* d_ws, size_t ws_size,
                              hipStream_t stream) {
  const float* x    = (const float*)d_in[0];
  const float* W    = (const float*)d_in[1];
  const float* pb   = (const float*)d_in[2];
  const float* mt   = (const float*)d_in[3];
  const float* gmm  = (const float*)d_in[4];
  const float* bta  = (const float*)d_in[5];
  const int*   perm = (const int*)d_in[6];
  float* out = (float*)d_out;
  float* out_idx = out + (long)NBATCH * TOKN * EMB;   // 42,467,328

  float* tabg = (float*)d_ws;                         // 24 KB sincos table
  short* wsW  = (short*)((char*)d_ws + TABN * 4);     // 96 KB bf16 W^T [col][k]

  setup_kernel<<<(WN + NTHREADS - 1) / NTHREADS, NTHREADS, 0, stream>>>(
      W, perm, tabg, wsW, out_idx);
  fused_embed_ln_mfma<<<TOTBLOCKS, NTHREADS, 0, stream>>>(
      x, pb, mt, gmm, bta, perm, tabg, wsW, out);
}

// Round 7
// 215.597 us; speedup vs baseline: 1.1817x; 1.1569x over previous
//
#include <hip/hip_runtime.h>
#include <math.h>

// Problem constants
#define NTHREADS 256
#define TPB 32              // tokens per block (two 16-row MFMA tile-groups)
#define TOKN 13824          // 24*24*24
#define MASKN 10368         // 0.75 * TOKN
#define UNMASKN 3456        // TOKN - MASKN
#define EMB 768
#define NPOS 24
#define NBATCH 4
#define APB (UNMASKN / TPB)               // 108 unmask blocks per batch
#define ABLK (NBATCH * APB)               // 432
#define BBLK (MASKN / TPB)                // 324 (mask computed once, stored x4)
#define TOTBLK (ABLK + BBLK)              // 756
#define TABN (NPOS * 256)         // 6144 floats = 24 KB sincos table in d_ws
#define WN (64 * EMB)             // 49152 W elements

typedef __attribute__((ext_vector_type(8))) short short8;   // 8 bf16 = 4 VGPRs
typedef __attribute__((ext_vector_type(4))) float f32x4;

__device__ __forceinline__ short f2bf(float f) {
  union { float f; unsigned u; } c; c.f = f;
  unsigned u = c.u + 0x7FFFu + ((c.u >> 16) & 1u);   // RNE
  return (short)(u >> 16);
}

// Setup: sincos table + bf16-transposed W (wsW[col][k]) in d_ws + mask_idx out.
__global__ __launch_bounds__(NTHREADS) void setup_kernel(
    const float* __restrict__ W, const int* __restrict__ perm,
    float* __restrict__ tabg, short* __restrict__ wsW,
    float* __restrict__ out_idx)
{
  int i = blockIdx.x * NTHREADS + threadIdx.x;
  if (i < MASKN) out_idx[i] = (float)perm[i];
  if (i < TABN) {
    // inv_freq[j] = 10000^(-j/128) = 2^(-j * log2(10000)/128)
    const float c0 = 13.287712379549449f / 128.0f;
    int pos = i >> 8, e = i & 255, j = e >> 1;
    float s = (float)pos * exp2f(-(float)j * c0);
    tabg[i] = (e & 1) ? cosf(s) : sinf(s);
  }
  if (i < WN) {
    int col = i >> 6, k = i & 63;
    wsW[i] = f2bf(W[k * EMB + col]);   // wsW[col*64 + k]
  }
}

// Round-9 (R6 post-mortem): spill was NOT the cost (scratch shrank, time
// didn't); no RFO on 64B stores (FETCH ~23MB). The ~100us pin across ALL
// variants = front-end VMEM volume: every 16-token block re-read all 96KB
// of wsW (+48KB tabg), and R5/R6's copy-blocks RECOMPUTED the mask GEMM 4x
// (332MB of wsW L2->L1 traffic, ~1.2M wave VMEM instrs).
// FIX: 32 tokens/block (756 blocks), W fragments loaded ONCE per wave into
// registers (24 x short8 = 96 VGPRs) and reused for both 16-token groups;
// mask rows computed once, stored x4 (no recompute); direct f32x4 stores
// (no ldsOut); plain launch_bounds.
__global__ __launch_bounds__(NTHREADS) void fused_embed_ln_mfma(
    const float* __restrict__ x, const float* __restrict__ pb,
    const float* __restrict__ mt, const float* __restrict__ gmm,
    const float* __restrict__ bta, const int* __restrict__ perm,
    const float* __restrict__ tabg, const short* __restrict__ wsW,
    float* __restrict__ out)
{
  __shared__ __align__(16) short aLds[TPB][72];   // bf16 A, +8 pad (4.6 KB)
  __shared__ int segb[3][TPB];                    // h/w/d << 8 per row
  __shared__ float wred[16][4][2];                // per-group LN partials

  const int tid = threadIdx.x;
  const int blk = blockIdx.x;
  const bool isA = blk < ABLK;
  const int b  = isA ? (blk / APB) : 0;            // batch (A-side)
  const int u0 = isA ? ((blk % APB) * TPB) : 0;    // unmask row base
  const int m0 = isA ? 0 : ((blk - ABLK) * TPB);   // mask row base

  // --- stage 32 patch rows into LDS as bf16 (2 halves of 256 tasks) ---
  #pragma unroll
  for (int half = 0; half < 2; ++half) {
    int task = half * 256 + tid;
    int t = task >> 4, seg = task & 15;            // t in [0,32), seg in [0,16)
    int r = isA ? perm[MASKN + u0 + t] : perm[m0 + t];
    int h = r / 576; int rem = r - h * 576;
    int w = rem / 24; int d = rem - w * 24;
    if (seg < 3) segb[seg][t] = (seg == 0 ? h : (seg == 1 ? w : d)) << 8;

    float4 v;
    if (isA) {
      int ph = seg >> 2, pw = seg & 3;
      v = *(const float4*)(x +
          ((((long)b * 96 + h * 4 + ph) * 96 + (w * 4 + pw)) * 96 + d * 4));
    } else {
      v = *(const float4*)(mt + (long)(m0 + t) * 64 + seg * 4);
    }
    short4 s4; s4.x = f2bf(v.x); s4.y = f2bf(v.y); s4.z = f2bf(v.z); s4.w = f2bf(v.w);
    *(short4*)&aLds[t][seg * 4] = s4;
  }

  // --- W fragments into registers, ONCE per block (amortized over 32 tokens)
  const int wv = tid >> 6, lane = tid & 63;
  const int n16 = lane & 15, q = lane >> 4;
  const int q4 = q * 4;
  const int colbase = wv * 192;

  short8 wf0[12], wf1[12];   // statically indexed only (rule: no scratch)
  {
    const short* wp = wsW + (colbase + n16) * 64 + q * 8;
    #pragma unroll
    for (int jt = 0; jt < 12; ++jt) {
      wf0[jt] = *(const short8*)(wp + jt * 1024);        // jt*16 cols * 64 k
      wf1[jt] = *(const short8*)(wp + jt * 1024 + 32);
    }
  }
  __syncthreads();                                   // staging visible

  // --- two 16-token groups, W frags reused ---
  #pragma unroll
  for (int g = 0; g < 2; ++g) {
    const int trow = g * 16 + n16;
    short8 af0 = *(const short8*)&aLds[trow][q * 8];
    short8 af1 = *(const short8*)&aLds[trow][32 + q * 8];

    f32x4 acc[12];
    #pragma unroll
    for (int jt = 0; jt < 12; ++jt) {
      f32x4 c = {0.f, 0.f, 0.f, 0.f};
      c = __builtin_amdgcn_mfma_f32_16x16x32_bf16(wf0[jt], af0, c, 0, 0, 0);
      c = __builtin_amdgcn_mfma_f32_16x16x32_bf16(wf1[jt], af1, c, 0, 0, 0);
      acc[jt] = c;   // acc[jt][r] = out[token=trow][col = colbase+jt*16+q4+r]
    }

    // bias + pos-enc (float4), per-token LN partials
    const float* t0 = tabg + segb[0][trow];
    const float* t1 = tabg + segb[1][trow];
    const float* t2 = tabg + segb[2][trow];
    float s = 0.f, qq = 0.f;
    #pragma unroll
    for (int jt = 0; jt < 12; ++jt) {
      int colb = colbase + jt * 16 + q4;
      int seg = colb >> 8;
      int cb = colb & 255;
      const float* tp = (seg == 0) ? t0 : ((seg == 1) ? t1 : t2);
      f32x4 pbv = *(const f32x4*)(pb + colb);
      f32x4 tv  = *(const f32x4*)(tp + cb);
      float v0 = acc[jt][0] + pbv[0] + tv[0];
      float v1 = acc[jt][1] + pbv[1] + tv[1];
      float v2 = acc[jt][2] + pbv[2] + tv[2];
      float v3 = acc[jt][3] + pbv[3] + tv[3];
      acc[jt][0] = v0; acc[jt][1] = v1; acc[jt][2] = v2; acc[jt][3] = v3;
      s  += (v0 + v1) + (v2 + v3);
      qq += (v0 * v0 + v1 * v1) + (v2 * v2 + v3 * v3);
    }
    // token row lives in n16; reduce across q (lane bits 4,5) only
    s  += __shfl_xor(s,  16, 64);
    s  += __shfl_xor(s,  32, 64);
    qq += __shfl_xor(qq, 16, 64);
    qq += __shfl_xor(qq, 32, 64);
    if (lane < 16) { wred[lane][wv][0] = s; wred[lane][wv][1] = qq; }
    __syncthreads();

    float ss = wred[n16][0][0] + wred[n16][1][0] + wred[n16][2][0] + wred[n16][3][0];
    float qs = wred[n16][0][1] + wred[n16][1][1] + wred[n16][2][1] + wred[n16][3][1];
    float mean = ss * (1.0f / 768.0f);
    float var = qs * (1.0f / 768.0f) - mean * mean;  // biased, matches jnp.var
    float rstd = 1.0f / sqrtf(var + 0.001f);         // LN_EPS

    // normalize + direct f32x4 stores (mask rows broadcast to 4 batches)
    if (isA) {
      float* base = out + ((long)b * TOKN + u0 + trow) * EMB + colbase + q4;
      #pragma unroll
      for (int jt = 0; jt < 12; ++jt) {
        int colb = colbase + jt * 16 + q4;
        f32x4 gg = *(const f32x4*)(gmm + colb);
        f32x4 bb = *(const f32x4*)(bta + colb);
        f32x4 o;
        #pragma unroll
        for (int r = 0; r < 4; ++r) {
          float sc = rstd * gg[r];
          o[r] = acc[jt][r] * sc + (bb[r] - mean * sc);
        }
        *(f32x4*)(base + jt * 16) = o;
      }
    } else {
      float* base = out + ((long)UNMASKN + m0 + trow) * EMB + colbase + q4;
      #pragma unroll
      for (int jt = 0; jt < 12; ++jt) {
        int colb = colbase + jt * 16 + q4;
        f32x4 gg = *(const f32x4*)(gmm + colb);
        f32x4 bb = *(const f32x4*)(bta + colb);
        f32x4 o;
        #pragma unroll
        for (int r = 0; r < 4; ++r) {
          float sc = rstd * gg[r];
          o[r] = acc[jt][r] * sc + (bb[r] - mean * sc);
        }
        float* p = base + jt * 16;
        #pragma unroll
        for (int b4 = 0; b4 < NBATCH; ++b4) {
          *(f32x4*)p = o;
          p += (long)TOKN * EMB;
        }
      }
    }
    if (g == 0) __syncthreads();   // protect wred reuse by group 1
  }
}

extern "C" void kernel_launch(void* const* d_in, const int* in_sizes, int n_in,
                              void* d_out, int out_size, void* d_ws, size_t ws_size,
                              hipStream_t stream) {
  const float* x    = (const float*)d_in[0];
  const float* W    = (const float*)d_in[1];
  const float* pb   = (const float*)d_in[2];
  const float* mt   = (const float*)d_in[3];
  const float* gmm  = (const float*)d_in[4];
  const float* bta  = (const float*)d_in[5];
  const int*   perm = (const int*)d_in[6];
  float* out = (float*)d_out;
  float* out_idx = out + (long)NBATCH * TOKN * EMB;   // 42,467,328

  float* tabg = (float*)d_ws;                         // 24 KB sincos table
  short* wsW  = (short*)((char*)d_ws + TABN * 4);     // 96 KB bf16 W^T [col][k]

  setup_kernel<<<(WN + NTHREADS - 1) / NTHREADS, NTHREADS, 0, stream>>>(
      W, perm, tabg, wsW, out_idx);
  fused_embed_ln_mfma<<<TOTBLK, NTHREADS, 0, stream>>>(
      x, pb, mt, gmm, bta, perm, tabg, wsW, out);
}